// Round 2
// baseline (31.561 us; speedup 1.0000x reference)
//
#include <hip/hip_runtime.h>

// Problem constants (from reference)
#define BB 2
#define LL 1024
#define KK 30
#define NCH 416            // 16 positional + 16 D_neighbor RBF + 24*16 pair RBF
#define PER_BLOCK (KK * NCH)       // 12480 floats per (b,l)
#define NF4 (PER_BLOCK / 4)        // 3120 float4 per (b,l)

// _PAIRS from reference: (ia, ib) per pair slot
// [(0,0),(2,2),(3,3),(4,4),(1,0),(1,2),(1,3),(1,4),(0,2),(0,3),(0,4),
//  (4,2),(4,3),(3,2),(0,1),(2,1),(3,1),(4,1),(2,0),(3,0),(4,0),(2,4),(3,4),(2,3)]
__device__ __constant__ unsigned char PAIR_A[24] =
    {0,2,3,4,1,1,1,1,0,0,0,4,4,3,0,2,3,4,2,3,4,2,3,2};
__device__ __constant__ unsigned char PAIR_B[24] =
    {0,2,3,4,0,2,3,4,2,3,4,2,3,2,1,1,1,1,0,0,0,4,4,3};

// ---------------------------------------------------------------------------
// Kernel A: per-(b,l) prep — residue index (chain scan) + 5-atom table (w/ Cb)
// grid = B blocks of 1024 threads (thread == position l)
// ---------------------------------------------------------------------------
__global__ __launch_bounds__(1024)
void prep_kernel(const float* __restrict__ X, const int* __restrict__ chain_idx,
                 float* __restrict__ atomsG, int* __restrict__ ridxG)
{
    const int b  = blockIdx.x;
    const int l  = threadIdx.x;
    const int gi = b * LL + l;

    __shared__ int s[LL];

    // boundary: 1 where chain changes (boundary[0] = 0)
    const int ch     = chain_idx[gi];
    const int chPrev = (l > 0) ? chain_idx[gi - 1] : ch;
    s[l] = (ch != chPrev) ? 1 : 0;
    __syncthreads();

    // Hillis-Steele inclusive scan over 1024 elements
    for (int off = 1; off < LL; off <<= 1) {
        int add = (l >= off) ? s[l - off] : 0;
        __syncthreads();
        s[l] += add;
        __syncthreads();
    }
    const int cn   = s[l];       // chain number at l
    const int last = s[LL - 1];  // total transitions (num_chains - 1)
    ridxG[gi] = (cn < last) ? (100 * cn + l) : -100;

    // Atom table: N, Ca, C, O copied; Cb = -0.58273431*a + 0.56802827*b
    //             - 0.54067466*c + Ca,   a = cross(b, c), b = Ca-N, c = C-Ca
    const float* xp = X + gi * 12;
    const float N0 = xp[0],  N1 = xp[1],  N2 = xp[2];
    const float A0 = xp[3],  A1 = xp[4],  A2 = xp[5];   // Ca
    const float C0 = xp[6],  C1 = xp[7],  C2 = xp[8];
    const float O0 = xp[9],  O1 = xp[10], O2 = xp[11];

    const float bx = A0 - N0, by = A1 - N1, bz = A2 - N2;
    const float cx = C0 - A0, cy = C1 - A1, cz = C2 - A2;
    const float ax = by * cz - bz * cy;
    const float ay = bz * cx - bx * cz;
    const float az = bx * cy - by * cx;
    const float ka = -0.58273431f, kb = 0.56802827f, kc = -0.54067466f;
    const float Cb0 = ka * ax + kb * bx + kc * cx + A0;
    const float Cb1 = ka * ay + kb * by + kc * cy + A1;
    const float Cb2 = ka * az + kb * bz + kc * cz + A2;

    float* ap = atomsG + gi * 15;
    ap[0]  = N0;  ap[1]  = N1;  ap[2]  = N2;
    ap[3]  = A0;  ap[4]  = A1;  ap[5]  = A2;
    ap[6]  = C0;  ap[7]  = C1;  ap[8]  = C2;
    ap[9]  = O0;  ap[10] = O1;  ap[11] = O2;
    ap[12] = Cb0; ap[13] = Cb1; ap[14] = Cb2;
}

// ---------------------------------------------------------------------------
// Kernel B: one block per (b,l); 256 threads.
// Phases: stage W/b/latoms/jidx -> gather neighbor atoms + bucket idx ->
//         24*30 scaled distances -> coalesced float4 write of 12480 channels.
// ---------------------------------------------------------------------------
__global__ __launch_bounds__(256)
void feat_kernel(const float* __restrict__ atomsG, const int* __restrict__ ridxG,
                 const int* __restrict__ chainG, const int* __restrict__ E_idx,
                 const float* __restrict__ D_neighbors,
                 const float* __restrict__ W_pos, const float* __restrict__ b_pos,
                 float* __restrict__ out)
{
    __shared__ float Wlds[16 * 66];   // W_pos as-is (row-major 16x66)
    __shared__ float bpos[16];
    __shared__ float latm[16];        // own atoms (15 used)
    __shared__ float natm[KK][16];    // neighbor atoms (15 used, padded)
    __shared__ float pd[KK][26];      // scaled distances: [k][0]=0.8*Dnbr, [k][1+p]
    __shared__ int   jidx[KK];        // global row index of neighbor (b*L + j)
    __shared__ int   dd[KK];          // positional bucket 0..65
    __shared__ int   iaib[24];        // packed (3*ia)<<8 | (3*ib)

    const int tid = threadIdx.x;
    const int bi  = blockIdx.x;          // b*L + l
    const int l   = bi & (LL - 1);
    const int rowbase = bi - l;          // b*L

    // ---- P0: stage constants + own data -----------------------------------
    for (int i = tid; i < 16 * 66; i += 256) Wlds[i] = W_pos[i];
    if (tid < 16) bpos[tid] = b_pos[tid];
    if (tid < 15) latm[tid] = atomsG[bi * 15 + tid];
    if (tid < KK) {
        jidx[tid]  = rowbase + E_idx[bi * KK + tid];
        pd[tid][0] = D_neighbors[bi * KK + tid] * 0.8f;
    }
    if (tid < 24) {
        iaib[tid] = ((int)(3 * PAIR_A[tid]) << 8) | (int)(3 * PAIR_B[tid]);
    }
    __syncthreads();

    // ---- P1: gather neighbor atoms + positional bucket --------------------
    for (int i = tid; i < KK * 15; i += 256) {
        const int k = i / 15;
        const int r = i - k * 15;
        natm[k][r] = atomsG[jidx[k] * 15 + r];
    }
    if (tid < KK) {
        const int j  = jidx[tid];
        const int rl = ridxG[bi];
        const int rj = ridxG[j];
        const int same = (chainG[bi] == chainG[j]);
        int off = rl - rj + 32;
        off = off < 0 ? 0 : (off > 64 ? 64 : off);
        dd[tid] = same ? off : 65;
    }
    __syncthreads();

    // ---- P2: 30*24 pair distances (pre-scaled by 1/sigma = 0.8) -----------
    for (int i = tid; i < KK * 24; i += 256) {
        const int k  = i / 24;
        const int p  = i - k * 24;
        const int pk = iaib[p];
        const int ao = pk >> 8;
        const int bo = pk & 255;
        const float dx = latm[ao]     - natm[k][bo];
        const float dy = latm[ao + 1] - natm[k][bo + 1];
        const float dz = latm[ao + 2] - natm[k][bo + 2];
        const float D  = sqrtf(dx * dx + dy * dy + dz * dz + 1e-6f);
        pd[k][1 + p] = D * 0.8f;
    }
    __syncthreads();

    // ---- P3: coalesced float4 write of all 12480 channels -----------------
    float* outp = out + (size_t)bi * PER_BLOCK;
    const float MU0   = 1.6f;                   // 0.8 * 2.0
    const float MUSTEP = 1.0666666666666667f;   // 0.8 * (20/15)
    const float NLOG2E = -1.44269504088896f;

    for (int i4 = tid; i4 < NF4; i4 += 256) {
        const int k  = i4 / 104;                // 104 float4 per edge
        const int c0 = (i4 - k * 104) * 4;      // channel of .x
        float4 v;
        if (c0 < 16) {
            const int d = dd[k];
            v.x = Wlds[(c0 + 0) * 66 + d] + bpos[c0 + 0];
            v.y = Wlds[(c0 + 1) * 66 + d] + bpos[c0 + 1];
            v.z = Wlds[(c0 + 2) * 66 + d] + bpos[c0 + 2];
            v.w = Wlds[(c0 + 3) * 66 + d] + bpos[c0 + 3];
        } else {
            const int q  = (c0 - 16) >> 4;      // which distance (0=Dnbr, 1+p)
            const int m0 = (c0 - 16) & 15;      // RBF index of .x (0,4,8,12)
            const float D8 = pd[k][q];
            const float t0 = D8 - (MU0 + (float)(m0 + 0) * MUSTEP);
            const float t1 = D8 - (MU0 + (float)(m0 + 1) * MUSTEP);
            const float t2 = D8 - (MU0 + (float)(m0 + 2) * MUSTEP);
            const float t3 = D8 - (MU0 + (float)(m0 + 3) * MUSTEP);
            v.x = __builtin_amdgcn_exp2f(t0 * t0 * NLOG2E);
            v.y = __builtin_amdgcn_exp2f(t1 * t1 * NLOG2E);
            v.z = __builtin_amdgcn_exp2f(t2 * t2 * NLOG2E);
            v.w = __builtin_amdgcn_exp2f(t3 * t3 * NLOG2E);
        }
        *reinterpret_cast<float4*>(outp + i4 * 4) = v;
    }
}

// ---------------------------------------------------------------------------
extern "C" void kernel_launch(void* const* d_in, const int* in_sizes, int n_in,
                              void* d_out, int out_size, void* d_ws, size_t ws_size,
                              hipStream_t stream)
{
    const float* X           = (const float*)d_in[0];
    const int*   chain_idx   = (const int*)  d_in[1];
    // d_in[2] = mask: unused by the reference forward
    const int*   E_idx       = (const int*)  d_in[3];
    const float* D_neighbors = (const float*)d_in[4];
    const float* W_pos       = (const float*)d_in[5];
    const float* b_pos       = (const float*)d_in[6];
    float* out = (float*)d_out;

    // workspace layout: atoms table (B*L*15 f32) then ridx (B*L i32) = 128 KB
    float* atomsG = (float*)d_ws;
    int*   ridxG  = (int*)((char*)d_ws + (size_t)BB * LL * 15 * sizeof(float));

    prep_kernel<<<BB, LL, 0, stream>>>(X, chain_idx, atomsG, ridxG);
    feat_kernel<<<BB * LL, 256, 0, stream>>>(atomsG, ridxG, chain_idx, E_idx,
                                             D_neighbors, W_pos, b_pos, out);
}

// Round 3
// 25.117 us; speedup vs baseline: 1.2566x; 1.2566x over previous
//
#include <hip/hip_runtime.h>

// Problem constants (from reference)
#define BB 2
#define LL 1024
#define KK 30
#define NCH 416            // 16 positional + 16 D_neighbor RBF + 24*16 pair RBF
#define PER_BLOCK (KK * NCH)       // 12480 floats per (b,l)
#define NF4 (PER_BLOCK / 4)        // 3120 float4 per (b,l)

// _PAIRS from reference: (ia, ib) per pair slot
// [(0,0),(2,2),(3,3),(4,4),(1,0),(1,2),(1,3),(1,4),(0,2),(0,3),(0,4),
//  (4,2),(4,3),(3,2),(0,1),(2,1),(3,1),(4,1),(2,0),(3,0),(4,0),(2,4),(3,4),(2,3)]
__device__ __constant__ unsigned char PAIR_A[24] =
    {0,2,3,4,1,1,1,1,0,0,0,4,4,3,0,2,3,4,2,3,4,2,3,2};
__device__ __constant__ unsigned char PAIR_B[24] =
    {0,2,3,4,0,2,3,4,2,3,4,2,3,2,1,1,1,1,0,0,0,4,4,3};

// ---------------------------------------------------------------------------
// Fully fused: one block per (b,l); 256 threads.
// P0: stage W/b/iaib; whole-row chain presence mask (int4 + shfl-or reduce);
//     lanes 0..29 gather neighbor row of X + build 5-atom set (w/ Cb);
//     lane 30 builds own atom set.
// P1: lanes 0..29 compute positional bucket via popcount residue-index math.
//     all threads compute 30*24 scaled pair distances into LDS.
// P2: coalesced float4 write of all 12480 channels.
// ---------------------------------------------------------------------------
__global__ __launch_bounds__(256)
void feat_fused(const float* __restrict__ X, const int* __restrict__ chainG,
                const int* __restrict__ E_idx, const float* __restrict__ D_neighbors,
                const float* __restrict__ W_pos, const float* __restrict__ b_pos,
                float* __restrict__ out)
{
    __shared__ float Wlds[16 * 66];   // W_pos row-major 16x66
    __shared__ float bpos[16];
    __shared__ float latm[16];        // own atoms (15 used)
    __shared__ float natm[KK][16];    // neighbor atoms (15 used, padded)
    __shared__ float pd[KK][26];      // scaled dists: [k][0]=0.8*Dnbr, [k][1+p]
    __shared__ int   dd[KK];          // positional bucket 0..65
    __shared__ int   iaib[24];        // packed (3*ia)<<8 | (3*ib)
    __shared__ int   wmask[4];        // per-wave chain presence masks

    const int tid = threadIdx.x;
    const int bi  = blockIdx.x;          // b*L + l
    const int l   = bi & (LL - 1);
    const int rowbase = bi - l;          // b*L

    // ---- P0a: chain presence mask over the whole batch row ----------------
    // 256 threads x int4 = 1024 chain values (coalesced, L2-resident)
    const int4 cv = reinterpret_cast<const int4*>(chainG + rowbase)[tid];
    int pm = (1 << cv.x) | (1 << cv.y) | (1 << cv.z) | (1 << cv.w);
    #pragma unroll
    for (int off = 32; off >= 1; off >>= 1) pm |= __shfl_xor(pm, off, 64);
    if ((tid & 63) == 0) wmask[tid >> 6] = pm;

    // ---- P0b: stage constants -------------------------------------------
    for (int i = tid; i < 16 * 66; i += 256) Wlds[i] = W_pos[i];
    if (tid < 16) bpos[tid] = b_pos[tid];
    if (tid < 24) iaib[tid] = ((int)(3 * PAIR_A[tid]) << 8) | (int)(3 * PAIR_B[tid]);

    // ---- P0c: gather rows of X, build atom sets (N,Ca,C,O,Cb) ------------
    int jj = 0, chj = 0;
    if (tid < KK) {
        jj  = E_idx[bi * KK + tid];            // neighbor position in [0,L)
        chj = chainG[rowbase + jj];
        pd[tid][0] = D_neighbors[bi * KK + tid] * 0.8f;
    }
    if (tid <= KK) {
        const int j = (tid < KK) ? (rowbase + jj) : bi;   // lane 30 = own row
        const float4* xp = reinterpret_cast<const float4*>(X + (size_t)j * 12);
        const float4 x0 = xp[0], x1 = xp[1], x2 = xp[2];
        // N=(x0.x,x0.y,x0.z) Ca=(x0.w,x1.x,x1.y) C=(x1.z,x1.w,x2.x) O=(x2.y,x2.z,x2.w)
        const float bx = x0.w - x0.x, by = x1.x - x0.y, bz = x1.y - x0.z; // Ca-N
        const float cx = x1.z - x0.w, cy = x1.w - x1.x, cz = x2.x - x1.y; // C-Ca
        const float ax = by * cz - bz * cy;
        const float ay = bz * cx - bx * cz;
        const float az = bx * cy - by * cx;
        const float ka = -0.58273431f, kb = 0.56802827f, kc = -0.54067466f;
        float* ap = (tid < KK) ? &natm[tid][0] : &latm[0];
        ap[0]  = x0.x; ap[1]  = x0.y; ap[2]  = x0.z;          // N
        ap[3]  = x0.w; ap[4]  = x1.x; ap[5]  = x1.y;          // Ca
        ap[6]  = x1.z; ap[7]  = x1.w; ap[8]  = x2.x;          // C
        ap[9]  = x2.y; ap[10] = x2.z; ap[11] = x2.w;          // O
        ap[12] = ka * ax + kb * bx + kc * cx + x0.w;          // Cb
        ap[13] = ka * ay + kb * by + kc * cy + x1.x;
        ap[14] = ka * az + kb * bz + kc * cz + x1.y;
    }
    __syncthreads();

    // ---- P1a: positional bucket (residue-index math via presence mask) ---
    if (tid < KK) {
        const int mask = wmask[0] | wmask[1] | wmask[2] | wmask[3];
        const int chl  = chainG[bi];
        const int npres = __popc(mask);                    // = last + 1
        const int cl1 = __popc(mask & ((2 << chl) - 1));   // = cn_l + 1
        const int cj1 = __popc(mask & ((2 << chj) - 1));   // = cn_j + 1
        const int rl = (cl1 < npres) ? (100 * (cl1 - 1) + l)  : -100;
        const int rj = (cj1 < npres) ? (100 * (cj1 - 1) + jj) : -100;
        int off = rl - rj + 32;
        off = off < 0 ? 0 : (off > 64 ? 64 : off);
        dd[tid] = (chl == chj) ? off : 65;
    }

    // ---- P1b: 30*24 pair distances (pre-scaled by 1/sigma = 0.8) ---------
    for (int i = tid; i < KK * 24; i += 256) {
        const int k  = i / 24;
        const int p  = i - k * 24;
        const int pk = iaib[p];
        const int ao = pk >> 8;
        const int bo = pk & 255;
        const float dx = latm[ao]     - natm[k][bo];
        const float dy = latm[ao + 1] - natm[k][bo + 1];
        const float dz = latm[ao + 2] - natm[k][bo + 2];
        const float D  = sqrtf(dx * dx + dy * dy + dz * dz + 1e-6f);
        pd[k][1 + p] = D * 0.8f;
    }
    __syncthreads();

    // ---- P2: coalesced float4 write of all 12480 channels ----------------
    float* outp = out + (size_t)bi * PER_BLOCK;
    const float MU0    = 1.6f;                   // 0.8 * 2.0
    const float MUSTEP = 1.0666666666666667f;    // 0.8 * (20/15)
    const float NLOG2E = -1.44269504088896f;

    for (int i4 = tid; i4 < NF4; i4 += 256) {
        const int k  = i4 / 104;                // 104 float4 per edge
        const int c0 = (i4 - k * 104) * 4;      // channel of .x
        float4 v;
        if (c0 < 16) {
            const int d = dd[k];
            v.x = Wlds[(c0 + 0) * 66 + d] + bpos[c0 + 0];
            v.y = Wlds[(c0 + 1) * 66 + d] + bpos[c0 + 1];
            v.z = Wlds[(c0 + 2) * 66 + d] + bpos[c0 + 2];
            v.w = Wlds[(c0 + 3) * 66 + d] + bpos[c0 + 3];
        } else {
            const int q  = (c0 - 16) >> 4;      // which distance (0=Dnbr, 1+p)
            const int m0 = (c0 - 16) & 15;      // RBF index of .x (0,4,8,12)
            const float D8 = pd[k][q];
            const float t0 = D8 - (MU0 + (float)(m0 + 0) * MUSTEP);
            const float t1 = D8 - (MU0 + (float)(m0 + 1) * MUSTEP);
            const float t2 = D8 - (MU0 + (float)(m0 + 2) * MUSTEP);
            const float t3 = D8 - (MU0 + (float)(m0 + 3) * MUSTEP);
            v.x = __builtin_amdgcn_exp2f(t0 * t0 * NLOG2E);
            v.y = __builtin_amdgcn_exp2f(t1 * t1 * NLOG2E);
            v.z = __builtin_amdgcn_exp2f(t2 * t2 * NLOG2E);
            v.w = __builtin_amdgcn_exp2f(t3 * t3 * NLOG2E);
        }
        *reinterpret_cast<float4*>(outp + i4 * 4) = v;
    }
}

// ---------------------------------------------------------------------------
extern "C" void kernel_launch(void* const* d_in, const int* in_sizes, int n_in,
                              void* d_out, int out_size, void* d_ws, size_t ws_size,
                              hipStream_t stream)
{
    const float* X           = (const float*)d_in[0];
    const int*   chain_idx   = (const int*)  d_in[1];
    // d_in[2] = mask: unused by the reference forward
    const int*   E_idx       = (const int*)  d_in[3];
    const float* D_neighbors = (const float*)d_in[4];
    const float* W_pos       = (const float*)d_in[5];
    const float* b_pos       = (const float*)d_in[6];
    float* out = (float*)d_out;

    feat_fused<<<BB * LL, 256, 0, stream>>>(X, chain_idx, E_idx, D_neighbors,
                                            W_pos, b_pos, out);
}